// Round 4
// baseline (271.602 us; speedup 1.0000x reference)
//
#include <hip/hip_runtime.h>

// RandomShiftsAug: out[n][c][oh][ow] = x[n][c][wrap(max(ky+oh-4,0))][clamp(kx+ow-4,0,419)]
// Memory-bound shifted copy: 162.5 MB read + 162.5 MB write -> ~49-52us kernel floor.
// Headline dur_us carries ~200us of harness poison/restore (profile top-5 is all
// fillBufferAligned @ ~97us; our kernel is below the top-5 cutoff, i.e. <95us).
//
// R4 vs R3: fully BRANCHLESS unified path. Previously ~55% of waves (those touching
// row-lane 0/104 with kx!=0) diverged into a 4-scalar-load edge path (+4 VMEM issues
// per wave at ~1 active lane). Now: clamp the two aligned v4 indices into the row,
// load A/B, and select each output element by window index e_j = clamp(c0+j,0,419)
// - 4*i0c  (in [0,7], 7-cndmask 8-way select). Hand-verified on c0=-4..-1, 417..420,
// and interior. +~36 VALU/thread is free at ~5% VALUBusy; removes all divergence.

constexpr int N     = 128;
constexpr int C     = 9;
constexpr int H     = 84;
constexpr int W     = 420;
constexpr int PAD   = 4;
constexpr int OUT_H = 84;
constexpr int ROW_V4   = W / 4;                    // 105 float4 per row
constexpr int TOTAL_V4 = N * C * OUT_H * ROW_V4;   // 10,160,640 = 39,690 * 256

typedef float f32x4 __attribute__((ext_vector_type(4)));

__global__ __launch_bounds__(256)
void RandomShiftsAug_kernel(const float* __restrict__ x,
                            const int*   __restrict__ shift,
                            f32x4*       __restrict__ out) {
    const int i = blockIdx.x * 256 + threadIdx.x;   // exact cover, no loop

    const int row_id = i / ROW_V4;               // const-div -> magic mul
    const int lane   = i - row_id * ROW_V4;      // 0..104
    const int nc     = row_id / OUT_H;           // n*C + c (matches x layout)
    const int oh     = row_id - nc * OUT_H;
    const int n      = nc / C;

    const int kx = shift[2 * n]     - PAD;       // [-4, 4]
    const int ky = shift[2 * n + 1];             // [0, 8]

    int r = ky + oh - PAD;                       // [-4, 87]
    r = r < 0 ? 0 : r;                           // top edge replicate
    if (r >= H) r -= H;                          // vertical tile wrap (single wrap max)

    const f32x4* __restrict__ srcv =
        (const f32x4*)(x + ((size_t)nc * H + r) * W);   // row base 16B-aligned (W*4=1680)

    const int c0  = lane * 4 + kx;               // [-4, 420]
    const int i0  = c0 >> 2;                     // arithmetic: [-1, 105]
    const int i0c = min(max(i0, 0), ROW_V4 - 1); // clamp into row
    const int i1c = min(i0 + 1, ROW_V4 - 1);     // >=0 automatically

    const f32x4 A = srcv[i0c];                   // coalesced; neighbor-lane overlap = L1 hit
    const f32x4 B = srcv[i1c];

    const int base4 = i0c << 2;
    const int ebase = c0 - base4;                // [-4, 3]
    const int emax  = min(W - 1 - base4, 7);     // [3, 7]

    const float w0 = A.x, w1 = A.y, w2 = A.z, w3 = A.w;
    const float w4 = B.x, w5 = B.y, w6 = B.z, w7 = B.w;

    f32x4 v;
    float* vp = (float*)&v;
#pragma unroll
    for (int j = 0; j < 4; ++j) {
        int e = ebase + j;                       // window index before clamp
        e = e < 0 ? 0 : e;                       // left edge replicate
        e = e > emax ? emax : e;                 // right edge replicate
        const float p0 = (e & 1) ? w1 : w0;      // 8-way select, 7 cndmask
        const float p1 = (e & 1) ? w3 : w2;
        const float p2 = (e & 1) ? w5 : w4;
        const float p3 = (e & 1) ? w7 : w6;
        const float q0 = (e & 2) ? p1 : p0;
        const float q1 = (e & 2) ? p3 : p2;
        vp[j]          = (e & 4) ? q1 : q0;
    }
    __builtin_nontemporal_store(v, &out[i]);     // write-once stream
}

extern "C" void kernel_launch(void* const* d_in, const int* in_sizes, int n_in,
                              void* d_out, int out_size, void* d_ws, size_t ws_size,
                              hipStream_t stream) {
    const float* x     = (const float*)d_in[0];
    const int*   shift = (const int*)d_in[1];
    f32x4*       out   = (f32x4*)d_out;

    const int block = 256;
    const int grid  = TOTAL_V4 / block;          // 39,690 blocks, exact cover
    RandomShiftsAug_kernel<<<grid, block, 0, stream>>>(x, shift, out);
}